// Round 3
// baseline (82.297 us; speedup 1.0000x reference)
//
#include <hip/hip_runtime.h>
#include <math.h>

// Problem constants (from reference setup_inputs)
#define B_    32
#define C_    4
#define N_    16384
#define RES_  32

// One point per thread: 2048 blocks x 256 threads = 524288 = B*N threads.
// 8 blocks/CU -> 32 waves/CU (hardware max) for maximum outstanding gathers.
#define CHUNKS 64
#define TPB    256

// Kernel 1: grid = 2048 1D blocks, XCD-swizzled so each XCD (id%8 assumed)
// serves exactly 4 batches -> per-XCD gather working set 4*393KB = 1.6MB < 4MiB L2.
__global__ __launch_bounds__(TPB) void sym_main(
    const float* __restrict__ y_pred,   // (B, C, 4)
    const float* __restrict__ points,   // (B, N, 3)
    const float* __restrict__ cp,       // (B, RES, RES, RES, 3)
    float* __restrict__ partials)       // (B * CHUNKS)
{
  const int id   = blockIdx.x;
  const int xcd  = id & 7;
  const int slot = id >> 3;            // 0..255
  const int b     = xcd + 8 * (slot & 3);   // 4 distinct batches per XCD
  const int chunk = slot >> 2;              // 0..63

  // Plane params (uniform across block; scalar-cached loads)
  const float* yp = y_pred + b * (C_ * 4);
  float nx[C_], ny[C_], nz[C_], dd[C_];
#pragma unroll
  for (int c = 0; c < C_; ++c) {
    float ax = yp[c * 4 + 0];
    float ay = yp[c * 4 + 1];
    float az = yp[c * 4 + 2];
    float inv = 1.0f / sqrtf(ax * ax + ay * ay + az * az);
    nx[c] = ax * inv;
    ny[c] = ay * inv;
    nz[c] = az * inv;
    dd[c] = yp[c * 4 + 3];
  }

  const float* pb  = points + (size_t)b * (N_ * 3);
  const float* cpb = cp + (size_t)b * (RES_ * RES_ * RES_ * 3);

  const int p = chunk * TPB + threadIdx.x;   // one point per thread
  const float px = pb[p * 3 + 0];
  const float py = pb[p * 3 + 1];
  const float pz = pb[p * 3 + 2];

  // Phase 1: all 4 reflected vectors + gather indices (no memory deps).
  float rx[C_], ry[C_], rz[C_];
  int lin[C_];
#pragma unroll
  for (int c = 0; c < C_; ++c) {
    float dist = px * nx[c] + py * ny[c] + pz * nz[c] + dd[c];
    float t2 = 2.0f * dist;
    float x = px - t2 * nx[c];
    float y = py - t2 * ny[c];
    float z = pz - t2 * nz[c];
    rx[c] = x; ry[c] = y; rz[c] = z;
    int vx = (int)fminf(fmaxf(floorf(x * (float)RES_), 0.0f), (float)(RES_ - 1));
    int vy = (int)fminf(fmaxf(floorf(y * (float)RES_), 0.0f), (float)(RES_ - 1));
    int vz = (int)fminf(fmaxf(floorf(z * (float)RES_), 0.0f), (float)(RES_ - 1));
    lin[c] = ((vx * RES_ + vy) * RES_ + vz) * 3;
  }

  // Phase 2: issue all 4 gathers (12B -> global_load_dwordx3), all in flight.
  float cx[C_], cy[C_], cz[C_];
#pragma unroll
  for (int c = 0; c < C_; ++c) {
    cx[c] = cpb[lin[c] + 0];
    cy[c] = cpb[lin[c] + 1];
    cz[c] = cpb[lin[c] + 2];
  }

  // Phase 3: distances into independent accumulators.
  float a0 = 0.0f, a1 = 0.0f;
#pragma unroll
  for (int c = 0; c < C_; c += 2) {
    float dx0 = rx[c+0] - cx[c+0], dy0 = ry[c+0] - cy[c+0], dz0 = rz[c+0] - cz[c+0];
    float dx1 = rx[c+1] - cx[c+1], dy1 = ry[c+1] - cy[c+1], dz1 = rz[c+1] - cz[c+1];
    a0 += sqrtf(dx0 * dx0 + dy0 * dy0 + dz0 * dz0);
    a1 += sqrtf(dx1 * dx1 + dy1 * dy1 + dz1 * dz1);
  }
  float acc = a0 + a1;

  // Wave (64-lane) shuffle reduction, then cross-wave via LDS
#pragma unroll
  for (int off = 32; off > 0; off >>= 1)
    acc += __shfl_down(acc, off, 64);

  __shared__ float sred[TPB / 64];
  const int lane = threadIdx.x & 63;
  const int wave = threadIdx.x >> 6;
  if (lane == 0) sred[wave] = acc;
  __syncthreads();
  if (threadIdx.x == 0) {
    float tot = 0.0f;
#pragma unroll
    for (int w = 0; w < TPB / 64; ++w) tot += sred[w];
    partials[b * CHUNKS + chunk] = tot;
  }
}

// Kernel 2: single block. Sums the B*CHUNKS partials (fp64 accumulate for
// precision: raw sum is ~5e6), adds REG_COEF * mean_b(reg_loss[b]).
__global__ __launch_bounds__(256) void sym_final(
    const float* __restrict__ y_pred,
    const float* __restrict__ partials,
    float* __restrict__ out)
{
  __shared__ double sd[256];
  double acc = 0.0;
  for (int i = threadIdx.x; i < B_ * CHUNKS; i += 256)
    acc += (double)partials[i];
  acc *= (1.0 / (double)N_);   // mean over n folded into the b,c sum

  if (threadIdx.x < B_) {
    const int b = threadIdx.x;
    const float* yp = y_pred + b * (C_ * 4);
    float nh[C_][3];
#pragma unroll
    for (int c = 0; c < C_; ++c) {
      float ax = yp[c * 4 + 0];
      float ay = yp[c * 4 + 1];
      float az = yp[c * 4 + 2];
      float inv = 1.0f / sqrtf(ax * ax + ay * ay + az * az);
      nh[c][0] = ax * inv;
      nh[c][1] = ay * inv;
      nh[c][2] = az * inv;
    }
    float s = 0.0f;
#pragma unroll
    for (int c = 0; c < C_; ++c) {
#pragma unroll
      for (int e = 0; e < C_; ++e) {
        float dot = nh[c][0] * nh[e][0] + nh[c][1] * nh[e][1] + nh[c][2] * nh[e][2];
        float g = dot - ((c == e) ? 1.0f : 0.0f);
        s += g * g;
      }
    }
    acc += (25.0 / (double)B_) * (double)sqrtf(s);
  }

  sd[threadIdx.x] = acc;
  __syncthreads();
  for (int off = 128; off > 0; off >>= 1) {
    if (threadIdx.x < off) sd[threadIdx.x] += sd[threadIdx.x + off];
    __syncthreads();
  }
  if (threadIdx.x == 0) out[0] = (float)sd[0];
}

extern "C" void kernel_launch(void* const* d_in, const int* in_sizes, int n_in,
                              void* d_out, int out_size, void* d_ws, size_t ws_size,
                              hipStream_t stream) {
  const float* y_pred = (const float*)d_in[0];   // (32,4,4)
  const float* points = (const float*)d_in[1];   // (32,16384,3)
  // d_in[2] = voxel_grid — unused by the reference loss
  const float* cp     = (const float*)d_in[3];   // (32,32,32,32,3)
  float* partials = (float*)d_ws;                // B_*CHUNKS floats
  float* out = (float*)d_out;

  sym_main<<<B_ * CHUNKS, TPB, 0, stream>>>(y_pred, points, cp, partials);
  sym_final<<<1, 256, 0, stream>>>(y_pred, partials, out);
}